// Round 2
// baseline (510.803 us; speedup 1.0000x reference)
//
#include <hip/hip_runtime.h>
#include <stdint.h>

#define S_DIM 4096
#define K_TOP 64
#define THREADS 256
#define EPT 16           // elements per thread = 4096/256
#define CAND_MAX 256

__global__ __launch_bounds__(256) void fill_ones_kernel(int4* __restrict__ out, int n4) {
    int i = blockIdx.x * blockDim.x + threadIdx.x;
    const int stride = gridDim.x * blockDim.x;
    const int4 v = make_int4(1, 1, 1, 1);
    for (; i < n4; i += stride) out[i] = v;
}

__global__ __launch_bounds__(256) void topk_scatter_kernel(const float* __restrict__ scores,
                                                           int* __restrict__ out) {
    const int row = blockIdx.x;           // b*S + s
    const int b   = row >> 12;            // row / 4096
    const int t   = threadIdx.x;

    __shared__ uint32_t hist[256];
    __shared__ uint32_t sfx[256];
    __shared__ unsigned long long cand[CAND_MAX];
    __shared__ uint32_t sh_prefix, sh_remaining, sh_count;

    // ---- load 16 floats per thread, coalesced float4 ----
    const float4* rowp = (const float4*)(scores + (size_t)row * S_DIM);
    uint32_t key[EPT];
    #pragma unroll
    for (int i = 0; i < 4; ++i) {
        float4 v = rowp[i * THREADS + t];
        float f[4] = {v.x, v.y, v.z, v.w};
        #pragma unroll
        for (int c = 0; c < 4; ++c) {
            uint32_t ub = __float_as_uint(f[c]);
            // monotonic map: larger float -> larger uint
            key[i * 4 + c] = (ub & 0x80000000u) ? ~ub : (ub | 0x80000000u);
        }
    }

    if (t == 0) { sh_count = 0u; }

    uint32_t prefix = 0u;
    uint32_t remaining = K_TOP;

    // ---- 4-pass radix select (8 bits/pass) for the 64th largest value ----
    #pragma unroll
    for (int pass = 0; pass < 4; ++pass) {
        const int shift = 24 - pass * 8;
        hist[t] = 0u;
        __syncthreads();

        #pragma unroll
        for (int i = 0; i < EPT; ++i) {
            uint32_t kk = key[i];
            bool active;
            if (pass == 0) active = true;
            else           active = ((kk ^ prefix) >> (shift + 8)) == 0u;
            if (active) atomicAdd(&hist[(kk >> shift) & 0xFFu], 1u);
        }
        __syncthreads();

        // suffix sum over 256 bins: after loop, hist[d] = count of active keys with digit >= d
        uint32_t* src = hist;
        uint32_t* dst = sfx;
        #pragma unroll
        for (int off = 1; off < 256; off <<= 1) {
            uint32_t v = src[t];
            if (t + off < 256) v += src[t + off];
            dst[t] = v;
            __syncthreads();
            uint32_t* tmp = src; src = dst; dst = tmp;
        }
        // 8 doubling steps (even count) -> result lands back in `src`
        uint32_t ge = src[t];
        uint32_t gt = (t == 255) ? 0u : src[t + 1];
        if (ge >= remaining && gt < remaining) {
            sh_prefix    = prefix | ((uint32_t)t << shift);
            sh_remaining = remaining - gt;
        }
        __syncthreads();
        prefix    = sh_prefix;
        remaining = sh_remaining;
    }

    const uint32_t T = prefix;  // exact 64th-largest key value (with multiplicity)

    // ---- collect all candidates with value >= T ----
    #pragma unroll
    for (int i = 0; i < EPT; ++i) {
        if (key[i] >= T) {
            uint32_t idx = (((uint32_t)(i >> 2) * THREADS + (uint32_t)t) << 2) | (uint32_t)(i & 3);
            uint32_t pos = atomicAdd(&sh_count, 1u);
            if (pos < CAND_MAX) {
                // 64-bit key: value desc primary, index asc secondary (~idx: smaller idx -> larger key)
                cand[pos] = ((unsigned long long)key[i] << 32) | (uint32_t)(~idx);
            }
        }
    }
    __syncthreads();

    uint32_t m = sh_count;
    if (m > CAND_MAX) m = CAND_MAX;

    // ---- rank candidates (distinct 64-bit keys), scatter zeros ----
    if ((uint32_t)t < m) {
        unsigned long long me = cand[t];
        uint32_t rank = 0;
        for (uint32_t i = 0; i < m; ++i) rank += (cand[i] > me) ? 1u : 0u;
        if (rank < K_TOP) {
            uint32_t idx = ~(uint32_t)me;      // recover original index
            // triangle overwrite (rows <= K, cols > row forced True) => skip iff idx < rank
            if (idx >= rank) {
                out[(size_t)b * ((size_t)S_DIM * S_DIM) + (size_t)idx * S_DIM + rank] = 0;
            }
        }
    }
}

extern "C" void kernel_launch(void* const* d_in, const int* in_sizes, int n_in,
                              void* d_out, int out_size, void* d_ws, size_t ws_size,
                              hipStream_t stream) {
    const float* scores = (const float*)d_in[0];
    int* out = (int*)d_out;

    const int n4 = out_size / 4;  // 67108864 / 4 = 16777216 int4s
    hipLaunchKernelGGL(fill_ones_kernel, dim3(2048), dim3(THREADS), 0, stream,
                       (int4*)out, n4);

    const int B = in_sizes[0] / (S_DIM * S_DIM);   // 4
    hipLaunchKernelGGL(topk_scatter_kernel, dim3(B * S_DIM), dim3(THREADS), 0, stream,
                       scores, out);
}

// Round 3
// 455.888 us; speedup vs baseline: 1.1205x; 1.1205x over previous
//
#include <hip/hip_runtime.h>
#include <stdint.h>

#define S_DIM 4096
#define K_TOP 64
#define THREADS 256
#define EPT 16           // elements per thread = 4096/256
#define CAND_CAP 256

__global__ __launch_bounds__(256) void fill_ones_kernel(int4* __restrict__ out, int n4) {
    int i = blockIdx.x * blockDim.x + threadIdx.x;
    const int stride = gridDim.x * blockDim.x;
    const int4 v = make_int4(1, 1, 1, 1);
    for (; i < n4; i += stride) out[i] = v;
}

__device__ __forceinline__ unsigned long long shfl_xor_u64(unsigned long long v, int m) {
    uint32_t lo = (uint32_t)v, hi = (uint32_t)(v >> 32);
    lo = __shfl_xor(lo, m, 64);
    hi = __shfl_xor(hi, m, 64);
    return ((unsigned long long)hi << 32) | lo;
}

__global__ __launch_bounds__(256) void topk_scatter_kernel(const float* __restrict__ scores,
                                                           int* __restrict__ out) {
    const int row  = blockIdx.x;          // b*S + s
    const int b    = row >> 12;           // row / 4096
    const int t    = threadIdx.x;
    const int lane = t & 63;
    const int wid  = t >> 6;

    __shared__ uint32_t sh_w16[4];
    __shared__ unsigned long long cand[CAND_CAP];
    __shared__ uint32_t sh_count;
    __shared__ unsigned long long sh_wbest[4];
    __shared__ unsigned long long sh_best;

    // ---- load 16 floats per thread, coalesced float4; monotonic u32 keys ----
    const float4* rowp = (const float4*)(scores + (size_t)row * S_DIM);
    uint32_t key[EPT];
    #pragma unroll
    for (int i = 0; i < 4; ++i) {
        float4 v = rowp[i * THREADS + t];
        float f[4] = {v.x, v.y, v.z, v.w};
        #pragma unroll
        for (int c = 0; c < 4; ++c) {
            uint32_t ub = __float_as_uint(f[c]);
            key[i * 4 + c] = (ub & 0x80000000u) ? ~ub : (ub | 0x80000000u);
        }
    }

    if (t == 0) sh_count = 0u;

    // ---- per-thread max of 16 keys ----
    uint32_t mx = key[0];
    #pragma unroll
    for (int i = 1; i < EPT; ++i) mx = max(mx, key[i]);

    // ---- wave-level bitonic sort (ascending by lane) of the 64 lane-maxes ----
    uint32_t x = mx;
    #pragma unroll
    for (int k = 2; k <= 64; k <<= 1) {
        #pragma unroll
        for (int j = k >> 1; j > 0; j >>= 1) {
            uint32_t v = __shfl_xor(x, j, 64);
            bool keepMin = (((lane & j) == 0) == ((lane & k) == 0));
            x = keepMin ? min(x, v) : max(x, v);
        }
    }
    // 16th largest lane-max sits at lane 48 (0-based rank 48 of ascending 64)
    uint32_t w16 = __shfl(x, 48, 64);
    if (lane == 0) sh_w16[wid] = w16;
    __syncthreads();                                    // barrier 1

    // Tc = min over waves; guaranteed >= 64 elements have key >= Tc, and Tc <= T64
    const uint32_t Tc = min(min(sh_w16[0], sh_w16[1]), min(sh_w16[2], sh_w16[3]));

    // ---- collect candidates: all elements with key >= Tc ----
    #pragma unroll
    for (int i = 0; i < EPT; ++i) {
        if (key[i] >= Tc) {
            uint32_t idx = (((uint32_t)(i >> 2) * THREADS + (uint32_t)t) << 2) | (uint32_t)(i & 3);
            uint32_t pos = atomicAdd(&sh_count, 1u);
            if (pos < CAND_CAP) {
                // 64-bit composite: value desc primary, index asc secondary (all distinct)
                cand[pos] = ((unsigned long long)key[i] << 32) | (uint32_t)(~idx);
            }
        }
    }
    __syncthreads();                                    // barrier 2
    const uint32_t m = sh_count;

    if (m <= CAND_CAP) {                                // block-uniform branch
        // ---- rank candidates (broadcast LDS reads, conflict-free), scatter zeros ----
        if ((uint32_t)t < m) {
            unsigned long long me = cand[t];
            uint32_t rank = 0;
            for (uint32_t i = 0; i < m; ++i) rank += (cand[i] > me) ? 1u : 0u;
            if (rank < K_TOP) {
                uint32_t idx = ~(uint32_t)me;
                // triangle (rows <= K, cols > row forced True) => skip iff idx < rank
                if (idx >= rank) {
                    out[(size_t)b * ((size_t)S_DIM * S_DIM) + (size_t)idx * S_DIM + rank] = 0;
                }
            }
        }
        return;
    }

    // ---- fallback (adversarial value-ties only): exact 64-round argmax extraction ----
    uint32_t used = 0u;
    for (int r = 0; r < K_TOP; ++r) {
        unsigned long long best = 0ull;
        #pragma unroll
        for (int i = 0; i < EPT; ++i) {
            if (!(used & (1u << i))) {
                uint32_t idx = (((uint32_t)(i >> 2) * THREADS + (uint32_t)t) << 2) | (uint32_t)(i & 3);
                unsigned long long ck = ((unsigned long long)key[i] << 32) | (uint32_t)(~idx);
                if (ck > best) best = ck;
            }
        }
        #pragma unroll
        for (int off = 32; off > 0; off >>= 1) {
            unsigned long long o = shfl_xor_u64(best, off);
            if (o > best) best = o;
        }
        if (lane == 0) sh_wbest[wid] = best;
        __syncthreads();
        if (t == 0) {
            unsigned long long bb = sh_wbest[0];
            for (int w = 1; w < 4; ++w) if (sh_wbest[w] > bb) bb = sh_wbest[w];
            sh_best = bb;
        }
        __syncthreads();
        const unsigned long long gb = sh_best;
        #pragma unroll
        for (int i = 0; i < EPT; ++i) {
            uint32_t idx = (((uint32_t)(i >> 2) * THREADS + (uint32_t)t) << 2) | (uint32_t)(i & 3);
            unsigned long long ck = ((unsigned long long)key[i] << 32) | (uint32_t)(~idx);
            if (ck == gb) {
                used |= (1u << i);
                uint32_t oidx = ~(uint32_t)gb;
                if (oidx >= (uint32_t)r) {
                    out[(size_t)b * ((size_t)S_DIM * S_DIM) + (size_t)oidx * S_DIM + r] = 0;
                }
            }
        }
        __syncthreads();
    }
}

extern "C" void kernel_launch(void* const* d_in, const int* in_sizes, int n_in,
                              void* d_out, int out_size, void* d_ws, size_t ws_size,
                              hipStream_t stream) {
    const float* scores = (const float*)d_in[0];
    int* out = (int*)d_out;

    const int n4 = out_size / 4;  // 67108864 / 4 = 16777216 int4s
    hipLaunchKernelGGL(fill_ones_kernel, dim3(2048), dim3(THREADS), 0, stream,
                       (int4*)out, n4);

    const int B = in_sizes[0] / (S_DIM * S_DIM);   // 4
    hipLaunchKernelGGL(topk_scatter_kernel, dim3(B * S_DIM), dim3(THREADS), 0, stream,
                       scores, out);
}